// Round 2
// baseline (935.924 us; speedup 1.0000x reference)
//
#include <hip/hip_runtime.h>
#include <math.h>

#define B_    32
#define H_    32
#define D_    128
#define KVH_  8
#define G_    4
#define P_    2048
#define T_    64
#define PPS_  64
#define NCHUNK 16
#define CHUNK_PAGES 4          // 256 tokens per chunk

// direct global->LDS DMA, 16B per lane, LDS dest = wave-uniform base + lane*16
__device__ __forceinline__ void load_lds16(const float4* g, void* l) {
    __builtin_amdgcn_global_load_lds(
        (const __attribute__((address_space(1))) void*)g,
        (__attribute__((address_space(3))) void*)l, 16, 0, 0);
}

// ---------------- Kernel 1: per-(b, kv-head, chunk) flash-decode partial ----------------
__global__ __launch_bounds__(256, 4)
void pa_partial(const float* __restrict__ q,
                const float* __restrict__ k_pages,
                const float* __restrict__ v_pages,
                const int*   __restrict__ lengths,
                const int*   __restrict__ page_indices,
                float* __restrict__ o_part,   // [4096][G*D]
                float* __restrict__ m_part,   // [4096][G]
                float* __restrict__ l_part)   // [4096][G]
{
    // K page, XOR-swizzled: element (t,j) lives at slot t*32 + (j ^ (t&7))
    __shared__ float4 K4s[T_ * 32];      // 32 KiB
    __shared__ float4 q4s[G_ * 32];      // 2 KiB
    __shared__ float  p_s[G_ * T_];      // 1 KiB
    __shared__ float  alpha_s[G_];

    const int tid = threadIdx.x;
    const int bx  = blockIdx.x;
    const int c   = bx & (NCHUNK - 1);
    const int k   = (bx >> 4) & (KVH_ - 1);
    const int b   = bx >> 7;

    const int len = lengths[b];
    if (c * (CHUNK_PAGES * T_) >= len) return;     // uniform early exit

    const int nP = (len + T_ - 1) >> 6;
    const int p0 = c * CHUNK_PAGES;
    const int p1 = min(nP, p0 + CHUNK_PAGES);

    // stage q[b, k*G .. k*G+3, :] (512 floats)
    {
        const float* qg = q + ((size_t)b * H_ + (size_t)k * G_) * D_;
        ((float*)q4s)[tid]       = qg[tid];
        ((float*)q4s)[tid + 256] = qg[tid + 256];
    }

    const int g  = tid >> 6;       // wave = head
    const int t  = tid & 63;       // lane = token
    const int dq = tid & 31;       // PV: float4 column
    const int th = tid >> 5;       // PV: token octet

    const int* pt = page_indices + b * PPS_;

    float m_run = -INFINITY;
    float l_run = 0.f;
    float4 oacc[G_];
#pragma unroll
    for (int i = 0; i < G_; ++i) { oacc[i].x = 0.f; oacc[i].y = 0.f; oacc[i].z = 0.f; oacc[i].w = 0.f; }

    // stage one K page into LDS via global_load_lds, swizzled destination
    auto stageK = [&](const float4* Kg) {
#pragma unroll
        for (int i = 0; i < 8; ++i) {
            const int Lb = (g * 8 + i) * 64;            // wave-uniform LDS base slot
            const int t_ = (Lb >> 5) + (t >> 5);        // row this lane feeds
            const int j_ = (t & 31) ^ (t_ & 7);         // swizzled source column
            load_lds16(Kg + t_ * 32 + j_, (void*)&K4s[Lb]);
        }
    };

    stageK((const float4*)(k_pages + ((size_t)k * P_ + pt[p0]) * (T_ * D_)));

    for (int p = p0; p < p1; ++p) {
        __syncthreads();                               // A: K(p) in LDS (and q4s on first iter)

        // early V issue: latency hides behind the score phase
        const float4* Vg = (const float4*)(v_pages + ((size_t)k * P_ + pt[p]) * (T_ * D_));
        float4 vv[8];
#pragma unroll
        for (int tt = 0; tt < 8; ++tt) vv[tt] = Vg[(th * 8 + tt) * 32 + dq];

        // ---- scores: thread (g, t) dot over D=128, swizzle-corrected reads ----
        float s = 0.f;
        {
            const float4* Kr = &K4s[t * 32];
            const float4* qr = &q4s[g * 32];
            const int sw = t & 7;
#pragma unroll
            for (int i = 0; i < 32; ++i) {
                const float4 kv = Kr[i ^ sw];
                const float4 qv = qr[i];               // wave-uniform broadcast
                s += kv.x * qv.x + kv.y * qv.y + kv.z * qv.z + kv.w * qv.w;
            }
        }
        const int tok = (p << 6) + t;
        if (tok >= len) s = -1e30f;

        // ---- online softmax (per wave = per head) ----
        float smax = s;
#pragma unroll
        for (int off = 32; off; off >>= 1) smax = fmaxf(smax, __shfl_xor(smax, off));
        const float m_new = fmaxf(m_run, smax);
        const float pr    = __expf(s - m_new);
        const float alpha = __expf(m_run - m_new);     // first page: exp(-inf)=0
        float psum = pr;
#pragma unroll
        for (int off = 32; off; off >>= 1) psum += __shfl_xor(psum, off);
        l_run = alpha * l_run + psum;
        m_run = m_new;
        p_s[(g << 6) + t] = pr;
        if (t == 0) alpha_s[g] = alpha;
        __syncthreads();                               // B: p_s/alpha visible; vv drained

        // pipeline: next page's K streams during PV
        if (p + 1 < p1)
            stageK((const float4*)(k_pages + ((size_t)k * P_ + pt[p + 1]) * (T_ * D_)));

        // ---- PV accumulate: thread (dq, th), 8 tokens, all 4 heads ----
        const float a0 = alpha_s[0], a1 = alpha_s[1], a2 = alpha_s[2], a3 = alpha_s[3];
        oacc[0].x *= a0; oacc[0].y *= a0; oacc[0].z *= a0; oacc[0].w *= a0;
        oacc[1].x *= a1; oacc[1].y *= a1; oacc[1].z *= a1; oacc[1].w *= a1;
        oacc[2].x *= a2; oacc[2].y *= a2; oacc[2].z *= a2; oacc[2].w *= a2;
        oacc[3].x *= a3; oacc[3].y *= a3; oacc[3].z *= a3; oacc[3].w *= a3;
#pragma unroll
        for (int tt = 0; tt < 8; ++tt) {
            const int t2 = (th << 3) + tt;
            const float4 v4 = vv[tt];
            const float pv0 = p_s[t2];
            const float pv1 = p_s[64 + t2];
            const float pv2 = p_s[128 + t2];
            const float pv3 = p_s[192 + t2];
            oacc[0].x += pv0 * v4.x; oacc[0].y += pv0 * v4.y; oacc[0].z += pv0 * v4.z; oacc[0].w += pv0 * v4.w;
            oacc[1].x += pv1 * v4.x; oacc[1].y += pv1 * v4.y; oacc[1].z += pv1 * v4.z; oacc[1].w += pv1 * v4.w;
            oacc[2].x += pv2 * v4.x; oacc[2].y += pv2 * v4.y; oacc[2].z += pv2 * v4.z; oacc[2].w += pv2 * v4.w;
            oacc[3].x += pv3 * v4.x; oacc[3].y += pv3 * v4.y; oacc[3].z += pv3 * v4.z; oacc[3].w += pv3 * v4.w;
        }
    }

    // ---- combine the 8 token-octet partials (reuse K4s as scratch) ----
    float4* red = K4s;
#pragma unroll
    for (int g2 = 0; g2 < G_; ++g2) red[(th * G_ + g2) * 32 + dq] = oacc[g2];
    if (t == 0) { m_part[bx * G_ + g] = m_run; l_part[bx * G_ + g] = l_run; }
    __syncthreads();

    if (tid < 128) {
        const int gg = tid >> 5;
        const int dd = tid & 31;
        float4 sum; sum.x = 0.f; sum.y = 0.f; sum.z = 0.f; sum.w = 0.f;
#pragma unroll
        for (int t8 = 0; t8 < 8; ++t8) {
            const float4 v = red[(t8 * G_ + gg) * 32 + dd];
            sum.x += v.x; sum.y += v.y; sum.z += v.z; sum.w += v.w;
        }
        float4* op = (float4*)(o_part + (size_t)bx * (G_ * D_));
        op[gg * 32 + dd] = sum;
    }
}

// ---------------- Kernel 2: combine chunk partials ----------------
__global__ __launch_bounds__(128)
void pa_reduce(const float* __restrict__ o_part,
               const float* __restrict__ m_part,
               const float* __restrict__ l_part,
               const int*   __restrict__ lengths,
               float* __restrict__ out)
{
    const int bx = blockIdx.x;          // (b, k, g)
    const int gg = bx & 3;
    const int k  = (bx >> 2) & 7;
    const int b  = bx >> 5;
    const int len = lengths[b];
    const int nc  = (len + 255) >> 8;   // valid chunks, 1..16
    const int base = (b * KVH_ + k) * NCHUNK;

    float M = -INFINITY;
#pragma unroll
    for (int c = 0; c < NCHUNK; ++c)
        if (c < nc) M = fmaxf(M, m_part[(base + c) * G_ + gg]);

    const int d = threadIdx.x;
    float L = 0.f;
    float acc = 0.f;
#pragma unroll
    for (int c = 0; c < NCHUNK; ++c) {
        if (c < nc) {
            const float wc = __expf(m_part[(base + c) * G_ + gg] - M);
            L   += wc * l_part[(base + c) * G_ + gg];
            acc += wc * o_part[(size_t)(base + c) * (G_ * D_) + gg * D_ + d];
        }
    }
    out[((size_t)b * H_ + (size_t)k * G_ + gg) * D_ + d] = acc / L;
}

extern "C" void kernel_launch(void* const* d_in, const int* in_sizes, int n_in,
                              void* d_out, int out_size, void* d_ws, size_t ws_size,
                              hipStream_t stream) {
    const float* q            = (const float*)d_in[0];
    const float* k_pages      = (const float*)d_in[1];
    const float* v_pages      = (const float*)d_in[2];
    const int*   lengths      = (const int*)d_in[3];
    const int*   page_indices = (const int*)d_in[4];
    float* out = (float*)d_out;

    const int nblk = B_ * KVH_ * NCHUNK;                           // 4096
    float* o_part = (float*)d_ws;                                  // 4096*512 floats = 8 MiB
    float* m_part = o_part + (size_t)nblk * (G_ * D_);
    float* l_part = m_part + (size_t)nblk * G_;

    pa_partial<<<nblk, 256, 0, stream>>>(
        q, k_pages, v_pages, lengths, page_indices, o_part, m_part, l_part);
    pa_reduce<<<B_ * KVH_ * G_, 128, 0, stream>>>(
        o_part, m_part, l_part, lengths, out);
}